// Round 10
// baseline (193.527 us; speedup 1.0000x reference)
//
#include <hip/hip_runtime.h>

// MultiModelMLP, round 10: memset + 2 kernels, register-resident mlp.
// phi-permuted weights make the MFMA D->B inter-layer transform lane-local:
// phi(16mt+4q+r) = 32(mt>>1)+8q+4(mt&1)+r. Epilogue RETURNS B-fragments by
// value (round 9's out-pointers escaped the local arrays -> scratch spills,
// 152 MB WRITE_SIZE, VGPR stuck at 64).

#define NM    64
#define HIDD  64
#define INF   6
#define OUTF  3
#define CAP   4864            // per-model capacity: mean 4096 + 12 sigma
#define NBLKB 128             // bucket kernel grid (2 blocks per model image)

#define CSTRIDE   32
#define O_CURSORS 0           // 64 cursors, stride 32 ints; final = count
#define O_ORDER   2048        // NM*CAP sample ids
#define IWS_INTS  (O_ORDER + NM * CAP)
// then: xs fp16[NM*CAP*8] (packed L0 inputs), then weight image.

// fp16 image per model, fragment-major (slot s in [0,1920), lane l = s&63
// holds its v8h at half-offset s*8); A-tile rows permuted by phi:
//   f = s>>6:  f<4: L0 mt=f (K padded 6->32)
//              f<28: L1..3: l=(f-4)>>3, mt=((f-4)&7)>>1, kh=(f-4)&1
//              else: L4 kh=f-28 (rows physical, padded 3->16)
// floats at byte CONST_B: l=0..3 {bias[64], g[64], h[64]} (phi-permuted),
// B4[3], pad.
#define CONST_B   30720
#define NCONSTF   784
#define IMG_BYTES 33856

typedef _Float16 v8h __attribute__((ext_vector_type(8)));
typedef __fp16   v2hf __attribute__((ext_vector_type(2)));
typedef float    v4f __attribute__((ext_vector_type(4)));

struct BF { v8h lo, hi; };

__device__ __host__ __forceinline__ int phi(int p) {
    int mt = p >> 4, q = (p >> 2) & 3, r = p & 3;
    return ((mt >> 1) << 5) | (q << 3) | ((mt & 1) << 2) | r;
}

// ------------------------------------------------------------ kernel 1 ----
__global__ __launch_bounds__(256, 4) void bucket_img_kernel(
    const int* __restrict__ idx, const float* __restrict__ x, int n,
    const float* __restrict__ W0, const float* __restrict__ W1,
    const float* __restrict__ W2, const float* __restrict__ W3,
    const float* __restrict__ W4,
    const float* __restrict__ B0, const float* __restrict__ G0, const float* __restrict__ H0,
    const float* __restrict__ B1, const float* __restrict__ G1, const float* __restrict__ H1,
    const float* __restrict__ B2, const float* __restrict__ G2, const float* __restrict__ H2,
    const float* __restrict__ B3, const float* __restrict__ G3, const float* __restrict__ H3,
    const float* __restrict__ B4,
    int* __restrict__ iws, _Float16* __restrict__ xs,
    unsigned char* __restrict__ imgbase) {
    __shared__ int lcnt[NM], lcur[NM];
    const int b = blockIdx.x, t = threadIdx.x;
    const int m = b >> 1, sub = b & 1;        // 2 blocks build each model image

    // ---- fragment-major image, rows phi-permuted ----
    _Float16* img = (_Float16*)(imgbase + (size_t)m * IMG_BYTES);
    float* cst = (float*)(imgbase + (size_t)m * IMG_BYTES + CONST_B);
    for (int s = sub * 256 + t; s < 1920; s += 512) {
        int f = s >> 6, l = s & 63;
        int c = l & 15, q = l >> 4;
        float vals[8];
        if (f < 4) {                          // layer 0, mt = f
            const float* wr = W0 + m * 384 + phi(f * 16 + c) * 6;
#pragma unroll
            for (int j = 0; j < 8; j++) {
                int k = q * 8 + j;
                vals[j] = (k < INF) ? wr[k] : 0.0f;
            }
        } else if (f < 28) {                  // layers 1..3
            int ll = (f - 4) >> 3, fb = (f - 4) & 7;
            int mt = fb >> 1, kh = fb & 1;
            const float* W = (ll == 0) ? W1 : (ll == 1) ? W2 : W3;
            const float* wr = W + m * 4096 + phi(mt * 16 + c) * 64 + kh * 32 + q * 8;
#pragma unroll
            for (int j = 0; j < 8; j++) vals[j] = wr[j];
        } else {                              // layer 4 (rows physical)
            int kh = f - 28;
            const float* wr = W4 + m * 192 + c * 64 + kh * 32 + q * 8;
#pragma unroll
            for (int j = 0; j < 8; j++) vals[j] = (c < OUTF) ? wr[j] : 0.0f;
        }
        v8h o;
#pragma unroll
        for (int j = 0; j < 8; j++) o[j] = (_Float16)vals[j];
        *(v8h*)(img + (size_t)s * 8) = o;
    }
    for (int e = sub * 256 + t; e < NCONSTF; e += 512) {   // consts, permuted
        const float* lsrc[12] = {B0, G0, H0, B1, G1, H1, B2, G2, H2, B3, G3, H3};
        float v = 0.0f;
        if (e < 768) {
            int l = e / 192, r = e - l * 192;
            v = lsrc[l * 3 + (r >> 6)][m * 64 + phi(r & 63)];
        } else if (e < 771) {
            v = B4[m * 3 + (e - 768)];
        }
        cst[e] = v;
    }

    // ---- pass 1: count this block's segment ----
    if (t < NM) lcnt[t] = 0;
    __syncthreads();
    const int per = (n + NBLKB - 1) / NBLKB;   // 2048
    const int beg = b * per, end = min(n, beg + per);
    for (int i = beg + t; i < end; i += 256) atomicAdd(&lcnt[idx[i]], 1);
    __syncthreads();
    if (t < NM) lcur[t] = atomicAdd(&iws[O_CURSORS + t * CSTRIDE], lcnt[t]);
    __syncthreads();
    // ---- pass 2: scatter ids + packed fp16 x ----
    for (int i = beg + t; i < end; i += 256) {
        int mm = idx[i];
        int r = atomicAdd(&lcur[mm], 1);      // LDS
        int slot = mm * CAP + r;
        iws[O_ORDER + slot] = i;
        const float* xp = x + (size_t)i * 6;
        float2 a0 = *(const float2*)(xp);
        float2 a1 = *(const float2*)(xp + 2);
        float2 a2 = *(const float2*)(xp + 4);
        v8h o = {};
        o[0] = (_Float16)a0.x; o[1] = (_Float16)a0.y;
        o[2] = (_Float16)a1.x; o[3] = (_Float16)a1.y;
        o[4] = (_Float16)a2.x; o[5] = (_Float16)a2.y;
        *(v8h*)(xs + (size_t)slot * 8) = o;
    }
}

// ------------------------------------------------------------ kernel 2 ----
// Epilogue: LN over 64 (phi-permuted) features + relu + pack straight into
// the next layer's B-fragments. RETURNS BY VALUE (no escaping pointers!).
__device__ __forceinline__ BF layer_epilogue(const v4f D[4],
                                             const float* __restrict__ cb,
                                             int q) {
    float S = 0.0f, Q2 = 0.0f;
#pragma unroll
    for (int mt = 0; mt < 4; mt++)
#pragma unroll
        for (int r = 0; r < 4; r++) {
            float v = D[mt][r];
            S += v;
            Q2 = fmaf(v, v, Q2);
        }
    S += __shfl_xor(S, 16, 64);
    S += __shfl_xor(S, 32, 64);
    Q2 += __shfl_xor(Q2, 16, 64);
    Q2 += __shfl_xor(Q2, 32, 64);
    float mu = S * (1.0f / 64.0f);
    float var = Q2 * (1.0f / 64.0f) - mu * mu;
    float rs = rsqrtf(var + 1e-5f);
    float nm = -mu * rs;
    v2hf pk[8];
#pragma unroll
    for (int mt = 0; mt < 4; mt++) {
        v4f g = *(const v4f*)(cb + 64 + mt * 16 + q * 4);
        v4f h = *(const v4f*)(cb + 128 + mt * 16 + q * 4);
        float y[4];
#pragma unroll
        for (int r = 0; r < 4; r++) {
            float tt = fmaf(D[mt][r], rs, nm);
            y[r] = fmaxf(fmaf(tt, g[r], h[r]), 0.0f);
        }
        pk[mt * 2]     = __builtin_amdgcn_cvt_pkrtz(y[0], y[1]);
        pk[mt * 2 + 1] = __builtin_amdgcn_cvt_pkrtz(y[2], y[3]);
    }
    BF r;
#pragma unroll
    for (int i = 0; i < 4; i++) {
        r.lo[i * 2]     = (_Float16)pk[i][0];
        r.lo[i * 2 + 1] = (_Float16)pk[i][1];
        r.hi[i * 2]     = (_Float16)pk[4 + i][0];
        r.hi[i * 2 + 1] = (_Float16)pk[4 + i][1];
    }
    return r;
}

__global__ __launch_bounds__(256, 4) void mlp_kernel(
    const int* __restrict__ iws, const _Float16* __restrict__ xs,
    const unsigned char* __restrict__ imgbase, float* __restrict__ out) {
    const int m = blockIdx.y;
    const int cnt = iws[O_CURSORS + m * CSTRIDE];
    const int beg = m * CAP, end = beg + cnt;
    const int base = beg + blockIdx.x * 256;
    if (base >= end) return;

    const int t = threadIdx.x, w = t >> 6, lane = t & 63;
    const int c = lane & 15, q = lane >> 4;
    const int wbase = base + w * 64;
    if (wbase >= end) return;

    const _Float16* img = (const _Float16*)(imgbase + (size_t)m * IMG_BYTES);
    const float* cf = (const float*)(imgbase + (size_t)m * IMG_BYTES + CONST_B);
    const int* order = iws + O_ORDER;

    int sid[4], sp[4];
#pragma unroll
    for (int ti = 0; ti < 4; ti++) {
        int p = wbase + ti * 16 + c;
        sp[ti] = p < end ? p : end - 1;
        sid[ti] = order[sp[ti]];
    }

    BF hb[4];

    // ---- layer 0: K=6 padded to 32; B from packed xs ----
    {
        v8h A[4];
#pragma unroll
        for (int mt = 0; mt < 4; mt++)
            A[mt] = *(const v8h*)(img + mt * 512 + lane * 8);
        v4f bias[4];
#pragma unroll
        for (int mt = 0; mt < 4; mt++)
            bias[mt] = *(const v4f*)(cf + mt * 16 + q * 4);
#pragma unroll
        for (int ti = 0; ti < 4; ti++) {
            v8h bfr = {};
            if (q == 0) bfr = *(const v8h*)(xs + (size_t)sp[ti] * 8);
            v4f D[4];
#pragma unroll
            for (int mt = 0; mt < 4; mt++)
                D[mt] = __builtin_amdgcn_mfma_f32_16x16x32_f16(A[mt], bfr, bias[mt], 0, 0, 0);
            hb[ti] = layer_epilogue(D, cf, q);
        }
    }

    // ---- layers 1..3: register-resident chaining, no LDS anywhere ----
#pragma unroll
    for (int l = 1; l <= 3; l++) {
        const _Float16* wp = img + 2048 + (l - 1) * 4096 + lane * 8;
        v8h A[4][2];
#pragma unroll
        for (int mt = 0; mt < 4; mt++)
#pragma unroll
            for (int kh = 0; kh < 2; kh++)
                A[mt][kh] = *(const v8h*)(wp + (mt * 2 + kh) * 512);
        const float* cb = cf + l * 192;
        v4f bias[4];
#pragma unroll
        for (int mt = 0; mt < 4; mt++)
            bias[mt] = *(const v4f*)(cb + mt * 16 + q * 4);
#pragma unroll
        for (int ti = 0; ti < 4; ti++) {
            v4f D[4];
#pragma unroll
            for (int mt = 0; mt < 4; mt++) {
                D[mt] = __builtin_amdgcn_mfma_f32_16x16x32_f16(A[mt][0], hb[ti].lo, bias[mt], 0, 0, 0);
                D[mt] = __builtin_amdgcn_mfma_f32_16x16x32_f16(A[mt][1], hb[ti].hi, D[mt], 0, 0, 0);
            }
            hb[ti] = layer_epilogue(D, cb, q);
        }
    }

    // ---- layer 4: 64 -> 3 (rows physical, padded to 16) ----
    {
        const _Float16* wp = img + 14336 + lane * 8;
        v8h A0 = *(const v8h*)(wp);
        v8h A1 = *(const v8h*)(wp + 512);
        v4f b4i = {cf[768], cf[769], cf[770], 0.0f};
#pragma unroll
        for (int ti = 0; ti < 4; ti++) {
            v4f D = __builtin_amdgcn_mfma_f32_16x16x32_f16(A0, hb[ti].lo, b4i, 0, 0, 0);
            D = __builtin_amdgcn_mfma_f32_16x16x32_f16(A1, hb[ti].hi, D, 0, 0, 0);
            int p = wbase + ti * 16 + c;
            if (q == 0 && p < end) {
                float* op = out + (size_t)sid[ti] * 3;
                op[0] = D[0]; op[1] = D[1]; op[2] = D[2];
            }
        }
    }
}

// -------------------------------------------------------------- launch ----
extern "C" void kernel_launch(void* const* d_in, const int* in_sizes, int n_in,
                              void* d_out, int out_size, void* d_ws, size_t ws_size,
                              hipStream_t stream) {
    const float* x  = (const float*)d_in[0];
    const int*  idx = (const int*)d_in[1];
    const float* W0 = (const float*)d_in[2];
    const float* B0 = (const float*)d_in[3];
    const float* G0 = (const float*)d_in[4];
    const float* H0 = (const float*)d_in[5];
    const float* W1 = (const float*)d_in[6];
    const float* B1 = (const float*)d_in[7];
    const float* G1 = (const float*)d_in[8];
    const float* H1 = (const float*)d_in[9];
    const float* W2 = (const float*)d_in[10];
    const float* B2 = (const float*)d_in[11];
    const float* G2 = (const float*)d_in[12];
    const float* H2 = (const float*)d_in[13];
    const float* W3 = (const float*)d_in[14];
    const float* B3 = (const float*)d_in[15];
    const float* G3 = (const float*)d_in[16];
    const float* H3 = (const float*)d_in[17];
    const float* W4 = (const float*)d_in[18];
    const float* B4 = (const float*)d_in[19];
    float* out = (float*)d_out;

    int n = in_sizes[1];
    int* iws = (int*)d_ws;
    _Float16* xs = (_Float16*)((char*)d_ws + (size_t)IWS_INTS * 4);
    unsigned char* imgbase =
        (unsigned char*)d_ws + (size_t)IWS_INTS * 4 + (size_t)NM * CAP * 16;

    (void)hipMemsetAsync(d_ws, 0, NM * CSTRIDE * sizeof(int), stream);
    bucket_img_kernel<<<dim3(NBLKB), 256, 0, stream>>>(
        idx, x, n, W0, W1, W2, W3, W4,
        B0, G0, H0, B1, G1, H1, B2, G2, H2, B3, G3, H3, B4, iws, xs, imgbase);
    // grid.x = ceil(CAP/256) = 19 chunks of 256 samples per model.
    mlp_kernel<<<dim3(19, NM), 256, 0, stream>>>(iws, xs, imgbase, out);
}

// Round 11
// 131.684 us; speedup vs baseline: 1.4696x; 1.4696x over previous
//
#include <hip/hip_runtime.h>

// MultiModelMLP, round 11: memset + 2 kernels, register-resident mlp with
// ZERO local arrays (rounds 9/10 spilled: allocas from D[4]/pk[8]/hb[4]
// never promoted -> 169 MB scratch WRITE). phi-permuted weights make the
// MFMA D->B inter-layer transform lane-local:
// phi(16mt+4q+r) = 32(mt>>1)+8q+4(mt&1)+r.

#define NM    64
#define HIDD  64
#define INF   6
#define OUTF  3
#define CAP   4864            // per-model capacity: mean 4096 + 12 sigma
#define NBLKB 128             // bucket kernel grid (2 blocks per model image)

#define CSTRIDE   32
#define O_CURSORS 0           // 64 cursors, stride 32 ints; final = count
#define O_ORDER   2048        // NM*CAP sample ids
#define IWS_INTS  (O_ORDER + NM * CAP)
// then: xs fp16[NM*CAP*8] (packed L0 inputs), then weight image.

#define CONST_B   30720
#define NCONSTF   784
#define IMG_BYTES 33856

typedef _Float16 v8h __attribute__((ext_vector_type(8)));
typedef __fp16   v2hf __attribute__((ext_vector_type(2)));
typedef float    v4f __attribute__((ext_vector_type(4)));

struct BF { v8h lo, hi; };
struct PK2 { v2hf a, b; };

__device__ __host__ __forceinline__ int phi(int p) {
    int mt = p >> 4, q = (p >> 2) & 3, r = p & 3;
    return ((mt >> 1) << 5) | (q << 3) | ((mt & 1) << 2) | r;
}

// ------------------------------------------------------------ kernel 1 ----
__global__ __launch_bounds__(256, 4) void bucket_img_kernel(
    const int* __restrict__ idx, const float* __restrict__ x, int n,
    const float* __restrict__ W0, const float* __restrict__ W1,
    const float* __restrict__ W2, const float* __restrict__ W3,
    const float* __restrict__ W4,
    const float* __restrict__ B0, const float* __restrict__ G0, const float* __restrict__ H0,
    const float* __restrict__ B1, const float* __restrict__ G1, const float* __restrict__ H1,
    const float* __restrict__ B2, const float* __restrict__ G2, const float* __restrict__ H2,
    const float* __restrict__ B3, const float* __restrict__ G3, const float* __restrict__ H3,
    const float* __restrict__ B4,
    int* __restrict__ iws, _Float16* __restrict__ xs,
    unsigned char* __restrict__ imgbase) {
    __shared__ int lcnt[NM], lcur[NM];
    const int b = blockIdx.x, t = threadIdx.x;
    const int m = b >> 1, sub = b & 1;        // 2 blocks build each model image

    _Float16* img = (_Float16*)(imgbase + (size_t)m * IMG_BYTES);
    float* cst = (float*)(imgbase + (size_t)m * IMG_BYTES + CONST_B);
    for (int s = sub * 256 + t; s < 1920; s += 512) {
        int f = s >> 6, l = s & 63;
        int c = l & 15, q = l >> 4;
        float vals[8];
        if (f < 4) {                          // layer 0, mt = f
            const float* wr = W0 + m * 384 + phi(f * 16 + c) * 6;
#pragma unroll
            for (int j = 0; j < 8; j++) {
                int k = q * 8 + j;
                vals[j] = (k < INF) ? wr[k] : 0.0f;
            }
        } else if (f < 28) {                  // layers 1..3
            int ll = (f - 4) >> 3, fb = (f - 4) & 7;
            int mt = fb >> 1, kh = fb & 1;
            const float* W = (ll == 0) ? W1 : (ll == 1) ? W2 : W3;
            const float* wr = W + m * 4096 + phi(mt * 16 + c) * 64 + kh * 32 + q * 8;
#pragma unroll
            for (int j = 0; j < 8; j++) vals[j] = wr[j];
        } else {                              // layer 4 (rows physical)
            int kh = f - 28;
            const float* wr = W4 + m * 192 + c * 64 + kh * 32 + q * 8;
#pragma unroll
            for (int j = 0; j < 8; j++) vals[j] = (c < OUTF) ? wr[j] : 0.0f;
        }
        v8h o;
#pragma unroll
        for (int j = 0; j < 8; j++) o[j] = (_Float16)vals[j];
        *(v8h*)(img + (size_t)s * 8) = o;
    }
    for (int e = sub * 256 + t; e < NCONSTF; e += 512) {   // consts, permuted
        const float* lsrc[12] = {B0, G0, H0, B1, G1, H1, B2, G2, H2, B3, G3, H3};
        float v = 0.0f;
        if (e < 768) {
            int l = e / 192, r = e - l * 192;
            v = lsrc[l * 3 + (r >> 6)][m * 64 + phi(r & 63)];
        } else if (e < 771) {
            v = B4[m * 3 + (e - 768)];
        }
        cst[e] = v;
    }

    if (t < NM) lcnt[t] = 0;
    __syncthreads();
    const int per = (n + NBLKB - 1) / NBLKB;   // 2048
    const int beg = b * per, end = min(n, beg + per);
    for (int i = beg + t; i < end; i += 256) atomicAdd(&lcnt[idx[i]], 1);
    __syncthreads();
    if (t < NM) lcur[t] = atomicAdd(&iws[O_CURSORS + t * CSTRIDE], lcnt[t]);
    __syncthreads();
    for (int i = beg + t; i < end; i += 256) {
        int mm = idx[i];
        int r = atomicAdd(&lcur[mm], 1);      // LDS
        int slot = mm * CAP + r;
        iws[O_ORDER + slot] = i;
        const float* xp = x + (size_t)i * 6;
        float2 a0 = *(const float2*)(xp);
        float2 a1 = *(const float2*)(xp + 2);
        float2 a2 = *(const float2*)(xp + 4);
        v8h o = {};
        o[0] = (_Float16)a0.x; o[1] = (_Float16)a0.y;
        o[2] = (_Float16)a1.x; o[3] = (_Float16)a1.y;
        o[4] = (_Float16)a2.x; o[5] = (_Float16)a2.y;
        *(v8h*)(xs + (size_t)slot * 8) = o;
    }
}

// ------------------------------------------------------------ kernel 2 ----
#define MFMA16(A, B, C) __builtin_amdgcn_mfma_f32_16x16x32_f16((A), (B), (C), 0, 0, 0)

__device__ __forceinline__ PK2 epi_quad(v4f dd, const float* gp, const float* hp,
                                        float rs, float nm) {
    v4f g = *(const v4f*)gp;
    v4f h = *(const v4f*)hp;
    float y0 = fmaxf(fmaf(fmaf(dd[0], rs, nm), g[0], h[0]), 0.0f);
    float y1 = fmaxf(fmaf(fmaf(dd[1], rs, nm), g[1], h[1]), 0.0f);
    float y2 = fmaxf(fmaf(fmaf(dd[2], rs, nm), g[2], h[2]), 0.0f);
    float y3 = fmaxf(fmaf(fmaf(dd[3], rs, nm), g[3], h[3]), 0.0f);
    PK2 r;
    r.a = __builtin_amdgcn_cvt_pkrtz(y0, y1);
    r.b = __builtin_amdgcn_cvt_pkrtz(y2, y3);
    return r;
}

// LN over 64 (phi-permuted) features + relu + pack into next-layer B-frags.
// All values, no arrays, no escaping pointers.
__device__ __forceinline__ BF layer_epilogue(v4f d0, v4f d1, v4f d2, v4f d3,
                                             const float* cb, int q) {
    float S = 0.0f, Q2 = 0.0f;
#pragma unroll
    for (int r = 0; r < 4; r++) {
        S += d0[r]; S += d1[r]; S += d2[r]; S += d3[r];
        Q2 = fmaf(d0[r], d0[r], Q2);
        Q2 = fmaf(d1[r], d1[r], Q2);
        Q2 = fmaf(d2[r], d2[r], Q2);
        Q2 = fmaf(d3[r], d3[r], Q2);
    }
    S += __shfl_xor(S, 16, 64);
    S += __shfl_xor(S, 32, 64);
    Q2 += __shfl_xor(Q2, 16, 64);
    Q2 += __shfl_xor(Q2, 32, 64);
    float mu = S * (1.0f / 64.0f);
    float var = Q2 * (1.0f / 64.0f) - mu * mu;
    float rs = rsqrtf(var + 1e-5f);
    float nm = -mu * rs;
    PK2 p0 = epi_quad(d0, cb + 64 + 0  + q * 4, cb + 128 + 0  + q * 4, rs, nm);
    PK2 p1 = epi_quad(d1, cb + 64 + 16 + q * 4, cb + 128 + 16 + q * 4, rs, nm);
    PK2 p2 = epi_quad(d2, cb + 64 + 32 + q * 4, cb + 128 + 32 + q * 4, rs, nm);
    PK2 p3 = epi_quad(d3, cb + 64 + 48 + q * 4, cb + 128 + 48 + q * 4, rs, nm);
    BF o;
    o.lo[0] = p0.a[0]; o.lo[1] = p0.a[1]; o.lo[2] = p0.b[0]; o.lo[3] = p0.b[1];
    o.lo[4] = p1.a[0]; o.lo[5] = p1.a[1]; o.lo[6] = p1.b[0]; o.lo[7] = p1.b[1];
    o.hi[0] = p2.a[0]; o.hi[1] = p2.a[1]; o.hi[2] = p2.b[0]; o.hi[3] = p2.b[1];
    o.hi[4] = p3.a[0]; o.hi[5] = p3.a[1]; o.hi[6] = p3.b[0]; o.hi[7] = p3.b[1];
    return o;
}

__device__ __forceinline__ BF l0_sample(const _Float16* xs, int sp, int q,
                                        v8h A0, v8h A1, v8h A2, v8h A3,
                                        v4f b0, v4f b1, v4f b2, v4f b3,
                                        const float* cf) {
    v8h bfr = {};
    if (q == 0) bfr = *(const v8h*)(xs + (size_t)sp * 8);
    v4f d0 = MFMA16(A0, bfr, b0);
    v4f d1 = MFMA16(A1, bfr, b1);
    v4f d2 = MFMA16(A2, bfr, b2);
    v4f d3 = MFMA16(A3, bfr, b3);
    return layer_epilogue(d0, d1, d2, d3, cf, q);
}

__device__ __forceinline__ BF mid_sample(BF h,
                                         v8h a00, v8h a01, v8h a10, v8h a11,
                                         v8h a20, v8h a21, v8h a30, v8h a31,
                                         v4f b0, v4f b1, v4f b2, v4f b3,
                                         const float* cb, int q) {
    v4f d0 = MFMA16(a00, h.lo, b0); d0 = MFMA16(a01, h.hi, d0);
    v4f d1 = MFMA16(a10, h.lo, b1); d1 = MFMA16(a11, h.hi, d1);
    v4f d2 = MFMA16(a20, h.lo, b2); d2 = MFMA16(a21, h.hi, d2);
    v4f d3 = MFMA16(a30, h.lo, b3); d3 = MFMA16(a31, h.hi, d3);
    return layer_epilogue(d0, d1, d2, d3, cb, q);
}

__global__ __launch_bounds__(256, 3) void mlp_kernel(
    const int* __restrict__ iws, const _Float16* __restrict__ xs,
    const unsigned char* __restrict__ imgbase, float* __restrict__ out) {
    const int m = blockIdx.y;
    const int cnt = iws[O_CURSORS + m * CSTRIDE];
    const int beg = m * CAP, end = beg + cnt;
    const int base = beg + blockIdx.x * 256;
    if (base >= end) return;

    const int t = threadIdx.x, w = t >> 6, lane = t & 63;
    const int c = lane & 15, q = lane >> 4;
    const int wbase = base + w * 64;
    if (wbase >= end) return;

    const _Float16* img = (const _Float16*)(imgbase + (size_t)m * IMG_BYTES);
    const float* cf = (const float*)(imgbase + (size_t)m * IMG_BYTES + CONST_B);
    const int* order = iws + O_ORDER;

    const int p0i = wbase + 0 + c,  p1i = wbase + 16 + c;
    const int p2i = wbase + 32 + c, p3i = wbase + 48 + c;
    const int sp0 = p0i < end ? p0i : end - 1;
    const int sp1 = p1i < end ? p1i : end - 1;
    const int sp2 = p2i < end ? p2i : end - 1;
    const int sp3 = p3i < end ? p3i : end - 1;
    const int sid0 = order[sp0], sid1 = order[sp1];
    const int sid2 = order[sp2], sid3 = order[sp3];

    BF h0, h1, h2, h3;

    // ---- layer 0: K=6 padded to 32; B from packed xs ----
    {
        v8h A0 = *(const v8h*)(img + 0 * 512 + lane * 8);
        v8h A1 = *(const v8h*)(img + 1 * 512 + lane * 8);
        v8h A2 = *(const v8h*)(img + 2 * 512 + lane * 8);
        v8h A3 = *(const v8h*)(img + 3 * 512 + lane * 8);
        v4f b0 = *(const v4f*)(cf + 0  + q * 4);
        v4f b1 = *(const v4f*)(cf + 16 + q * 4);
        v4f b2 = *(const v4f*)(cf + 32 + q * 4);
        v4f b3 = *(const v4f*)(cf + 48 + q * 4);
        h0 = l0_sample(xs, sp0, q, A0, A1, A2, A3, b0, b1, b2, b3, cf);
        h1 = l0_sample(xs, sp1, q, A0, A1, A2, A3, b0, b1, b2, b3, cf);
        h2 = l0_sample(xs, sp2, q, A0, A1, A2, A3, b0, b1, b2, b3, cf);
        h3 = l0_sample(xs, sp3, q, A0, A1, A2, A3, b0, b1, b2, b3, cf);
    }

    // ---- layers 1..3: register-resident chaining, no LDS, no arrays ----
    for (int l = 1; l <= 3; l++) {
        const _Float16* wp = img + 2048 + (l - 1) * 4096 + lane * 8;
        v8h a00 = *(const v8h*)(wp + 0 * 512);
        v8h a01 = *(const v8h*)(wp + 1 * 512);
        v8h a10 = *(const v8h*)(wp + 2 * 512);
        v8h a11 = *(const v8h*)(wp + 3 * 512);
        v8h a20 = *(const v8h*)(wp + 4 * 512);
        v8h a21 = *(const v8h*)(wp + 5 * 512);
        v8h a30 = *(const v8h*)(wp + 6 * 512);
        v8h a31 = *(const v8h*)(wp + 7 * 512);
        const float* cb = cf + l * 192;
        v4f b0 = *(const v4f*)(cb + 0  + q * 4);
        v4f b1 = *(const v4f*)(cb + 16 + q * 4);
        v4f b2 = *(const v4f*)(cb + 32 + q * 4);
        v4f b3 = *(const v4f*)(cb + 48 + q * 4);
        h0 = mid_sample(h0, a00, a01, a10, a11, a20, a21, a30, a31, b0, b1, b2, b3, cb, q);
        h1 = mid_sample(h1, a00, a01, a10, a11, a20, a21, a30, a31, b0, b1, b2, b3, cb, q);
        h2 = mid_sample(h2, a00, a01, a10, a11, a20, a21, a30, a31, b0, b1, b2, b3, cb, q);
        h3 = mid_sample(h3, a00, a01, a10, a11, a20, a21, a30, a31, b0, b1, b2, b3, cb, q);
    }

    // ---- layer 4: 64 -> 3 (rows physical, padded to 16) ----
    {
        const _Float16* wp = img + 14336 + lane * 8;
        v8h A0 = *(const v8h*)(wp);
        v8h A1 = *(const v8h*)(wp + 512);
        v4f b4i = {cf[768], cf[769], cf[770], 0.0f};
        v4f D0 = MFMA16(A0, h0.lo, b4i); D0 = MFMA16(A1, h0.hi, D0);
        v4f D1 = MFMA16(A0, h1.lo, b4i); D1 = MFMA16(A1, h1.hi, D1);
        v4f D2 = MFMA16(A0, h2.lo, b4i); D2 = MFMA16(A1, h2.hi, D2);
        v4f D3 = MFMA16(A0, h3.lo, b4i); D3 = MFMA16(A1, h3.hi, D3);
        if (q == 0) {
            if (p0i < end) { float* op = out + (size_t)sid0 * 3; op[0] = D0[0]; op[1] = D0[1]; op[2] = D0[2]; }
            if (p1i < end) { float* op = out + (size_t)sid1 * 3; op[0] = D1[0]; op[1] = D1[1]; op[2] = D1[2]; }
            if (p2i < end) { float* op = out + (size_t)sid2 * 3; op[0] = D2[0]; op[1] = D2[1]; op[2] = D2[2]; }
            if (p3i < end) { float* op = out + (size_t)sid3 * 3; op[0] = D3[0]; op[1] = D3[1]; op[2] = D3[2]; }
        }
    }
}

// -------------------------------------------------------------- launch ----
extern "C" void kernel_launch(void* const* d_in, const int* in_sizes, int n_in,
                              void* d_out, int out_size, void* d_ws, size_t ws_size,
                              hipStream_t stream) {
    const float* x  = (const float*)d_in[0];
    const int*  idx = (const int*)d_in[1];
    const float* W0 = (const float*)d_in[2];
    const float* B0 = (const float*)d_in[3];
    const float* G0 = (const float*)d_in[4];
    const float* H0 = (const float*)d_in[5];
    const float* W1 = (const float*)d_in[6];
    const float* B1 = (const float*)d_in[7];
    const float* G1 = (const float*)d_in[8];
    const float* H1 = (const float*)d_in[9];
    const float* W2 = (const float*)d_in[10];
    const float* B2 = (const float*)d_in[11];
    const float* G2 = (const float*)d_in[12];
    const float* H2 = (const float*)d_in[13];
    const float* W3 = (const float*)d_in[14];
    const float* B3 = (const float*)d_in[15];
    const float* G3 = (const float*)d_in[16];
    const float* H3 = (const float*)d_in[17];
    const float* W4 = (const float*)d_in[18];
    const float* B4 = (const float*)d_in[19];
    float* out = (float*)d_out;

    int n = in_sizes[1];
    int* iws = (int*)d_ws;
    _Float16* xs = (_Float16*)((char*)d_ws + (size_t)IWS_INTS * 4);
    unsigned char* imgbase =
        (unsigned char*)d_ws + (size_t)IWS_INTS * 4 + (size_t)NM * CAP * 16;

    (void)hipMemsetAsync(d_ws, 0, NM * CSTRIDE * sizeof(int), stream);
    bucket_img_kernel<<<dim3(NBLKB), 256, 0, stream>>>(
        idx, x, n, W0, W1, W2, W3, W4,
        B0, G0, H0, B1, G1, H1, B2, G2, H2, B3, G3, H3, B4, iws, xs, imgbase);
    // grid.x = ceil(CAP/256) = 19 chunks of 256 samples per model.
    mlp_kernel<<<dim3(19, NM), 256, 0, stream>>>(iws, xs, imgbase, out);
}

// Round 12
// 127.813 us; speedup vs baseline: 1.5141x; 1.0303x over previous
//
#include <hip/hip_runtime.h>

// MultiModelMLP, round 12: memset + 2 kernels.
// K1 bucket_img (256 blocks): two-pass queue-free bucketing (no register
//    queues -> no allocas/scratch) with FOUR two-ended cursor classes per
//    model (cls = blockIdx&3): global-atomic chain per cursor = 64.
// K2 mlp: R11's fully-scalarized register-resident fp16-MFMA pipeline
//    (phi-permuted weights make D->B lane-local), 3-interval validity masks.

#define NM    64
#define HIDD  64
#define INF   6
#define OUTF  3
#define CAP   4864            // per-model region: two halves of RHALF
#define RHALF 2432            // cls0 fwd from 0, cls1 bwd to RHALF,
                              // cls2 fwd from RHALF, cls3 bwd to CAP
#define NBLKB 256

#define CSTRIDE   32
#define O_CURSORS 0           // (m*4+cls)*CSTRIDE ints
#define O_ORDER   8192        // NM*CAP sample ids
#define IWS_INTS  (O_ORDER + NM * CAP)
// then: xs fp16[NM*CAP*8] (packed L0 inputs), then weight image.

#define CONST_B   30720
#define NCONSTF   784
#define IMG_BYTES 33856

typedef _Float16 v8h __attribute__((ext_vector_type(8)));
typedef __fp16   v2hf __attribute__((ext_vector_type(2)));
typedef float    v4f __attribute__((ext_vector_type(4)));

struct BF { v8h lo, hi; };
struct PK2 { v2hf a, b; };

__device__ __host__ __forceinline__ int phi(int p) {
    int mt = p >> 4, q = (p >> 2) & 3, r = p & 3;
    return ((mt >> 1) << 5) | (q << 3) | ((mt & 1) << 2) | r;
}

// ------------------------------------------------------------ kernel 1 ----
__global__ __launch_bounds__(256, 4) void bucket_img_kernel(
    const int* __restrict__ idx, const float* __restrict__ x, int n,
    const float* __restrict__ W0, const float* __restrict__ W1,
    const float* __restrict__ W2, const float* __restrict__ W3,
    const float* __restrict__ W4,
    const float* __restrict__ B0, const float* __restrict__ G0, const float* __restrict__ H0,
    const float* __restrict__ B1, const float* __restrict__ G1, const float* __restrict__ H1,
    const float* __restrict__ B2, const float* __restrict__ G2, const float* __restrict__ H2,
    const float* __restrict__ B3, const float* __restrict__ G3, const float* __restrict__ H3,
    const float* __restrict__ B4,
    int* __restrict__ iws, _Float16* __restrict__ xs,
    unsigned char* __restrict__ imgbase) {
    __shared__ int lcnt[NM], lcur[NM];
    const int b = blockIdx.x, t = threadIdx.x;
    const int m = b >> 2, sub = b & 3;        // 4 blocks build each model image
    const int cls = b & 3;                    // cursor class

    // ---- fragment-major image, rows phi-permuted ----
    _Float16* img = (_Float16*)(imgbase + (size_t)m * IMG_BYTES);
    float* cst = (float*)(imgbase + (size_t)m * IMG_BYTES + CONST_B);
    for (int s = sub * 256 + t; s < 1920; s += 1024) {
        int f = s >> 6, l = s & 63;
        int c = l & 15, q = l >> 4;
        float vals[8];
        if (f < 4) {                          // layer 0, mt = f
            const float* wr = W0 + m * 384 + phi(f * 16 + c) * 6;
#pragma unroll
            for (int j = 0; j < 8; j++) {
                int k = q * 8 + j;
                vals[j] = (k < INF) ? wr[k] : 0.0f;
            }
        } else if (f < 28) {                  // layers 1..3
            int ll = (f - 4) >> 3, fb = (f - 4) & 7;
            int mt = fb >> 1, kh = fb & 1;
            const float* W = (ll == 0) ? W1 : (ll == 1) ? W2 : W3;
            const float* wr = W + m * 4096 + phi(mt * 16 + c) * 64 + kh * 32 + q * 8;
#pragma unroll
            for (int j = 0; j < 8; j++) vals[j] = wr[j];
        } else {                              // layer 4 (rows physical)
            int kh = f - 28;
            const float* wr = W4 + m * 192 + c * 64 + kh * 32 + q * 8;
#pragma unroll
            for (int j = 0; j < 8; j++) vals[j] = (c < OUTF) ? wr[j] : 0.0f;
        }
        v8h o;
#pragma unroll
        for (int j = 0; j < 8; j++) o[j] = (_Float16)vals[j];
        *(v8h*)(img + (size_t)s * 8) = o;
    }
    {   // consts, permuted: sub*256+t covers [0,1024) > NCONSTF
        const float* lsrc[12] = {B0, G0, H0, B1, G1, H1, B2, G2, H2, B3, G3, H3};
        int e = sub * 256 + t;
        if (e < NCONSTF) {
            float v = 0.0f;
            if (e < 768) {
                int l = e / 192, r = e - l * 192;
                v = lsrc[l * 3 + (r >> 6)][m * 64 + phi(r & 63)];
            } else if (e < 771) {
                v = B4[m * 3 + (e - 768)];
            }
            cst[e] = v;
        }
    }

    // ---- pass 1: count this block's 1024-sample segment ----
    if (t < NM) { lcnt[t] = 0; lcur[t] = 0; }
    __syncthreads();
    const int per = (n + NBLKB - 1) / NBLKB;   // 1024
    const int beg = b * per, end = min(n, beg + per);
    for (int i = beg + t; i < end; i += 256) atomicAdd(&lcnt[idx[i]], 1);
    __syncthreads();
    __shared__ int lbase[NM];
    if (t < NM)
        lbase[t] = atomicAdd(&iws[O_CURSORS + (t * 4 + cls) * CSTRIDE], lcnt[t]);
    __syncthreads();
    // ---- pass 2: scatter ids + packed fp16 x (queue-free) ----
    for (int i = beg + t; i < end; i += 256) {
        int mm = idx[i];
        int r = atomicAdd(&lcur[mm], 1);      // LDS running rank
        int rel;
        if (cls == 0)      rel = lbase[mm] + r;
        else if (cls == 1) rel = RHALF - lbase[mm] - lcnt[mm] + r;
        else if (cls == 2) rel = RHALF + lbase[mm] + r;
        else               rel = CAP - lbase[mm] - lcnt[mm] + r;
        int slot = mm * CAP + rel;
        iws[O_ORDER + slot] = i;
        const float* xp = x + (size_t)i * 6;
        float2 a0 = *(const float2*)(xp);
        float2 a1 = *(const float2*)(xp + 2);
        float2 a2 = *(const float2*)(xp + 4);
        v8h o = {};
        o[0] = (_Float16)a0.x; o[1] = (_Float16)a0.y;
        o[2] = (_Float16)a1.x; o[3] = (_Float16)a1.y;
        o[4] = (_Float16)a2.x; o[5] = (_Float16)a2.y;
        *(v8h*)(xs + (size_t)slot * 8) = o;
    }
}

// ------------------------------------------------------------ kernel 2 ----
#define MFMA16(A, B, C) __builtin_amdgcn_mfma_f32_16x16x32_f16((A), (B), (C), 0, 0, 0)

__device__ __forceinline__ PK2 epi_quad(v4f dd, const float* gp, const float* hp,
                                        float rs, float nm) {
    v4f g = *(const v4f*)gp;
    v4f h = *(const v4f*)hp;
    float y0 = fmaxf(fmaf(fmaf(dd[0], rs, nm), g[0], h[0]), 0.0f);
    float y1 = fmaxf(fmaf(fmaf(dd[1], rs, nm), g[1], h[1]), 0.0f);
    float y2 = fmaxf(fmaf(fmaf(dd[2], rs, nm), g[2], h[2]), 0.0f);
    float y3 = fmaxf(fmaf(fmaf(dd[3], rs, nm), g[3], h[3]), 0.0f);
    PK2 r;
    r.a = __builtin_amdgcn_cvt_pkrtz(y0, y1);
    r.b = __builtin_amdgcn_cvt_pkrtz(y2, y3);
    return r;
}

__device__ __forceinline__ BF layer_epilogue(v4f d0, v4f d1, v4f d2, v4f d3,
                                             const float* cb, int q) {
    float S = 0.0f, Q2 = 0.0f;
#pragma unroll
    for (int r = 0; r < 4; r++) {
        S += d0[r]; S += d1[r]; S += d2[r]; S += d3[r];
        Q2 = fmaf(d0[r], d0[r], Q2);
        Q2 = fmaf(d1[r], d1[r], Q2);
        Q2 = fmaf(d2[r], d2[r], Q2);
        Q2 = fmaf(d3[r], d3[r], Q2);
    }
    S += __shfl_xor(S, 16, 64);
    S += __shfl_xor(S, 32, 64);
    Q2 += __shfl_xor(Q2, 16, 64);
    Q2 += __shfl_xor(Q2, 32, 64);
    float mu = S * (1.0f / 64.0f);
    float var = Q2 * (1.0f / 64.0f) - mu * mu;
    float rs = rsqrtf(var + 1e-5f);
    float nm = -mu * rs;
    PK2 p0 = epi_quad(d0, cb + 64 + 0  + q * 4, cb + 128 + 0  + q * 4, rs, nm);
    PK2 p1 = epi_quad(d1, cb + 64 + 16 + q * 4, cb + 128 + 16 + q * 4, rs, nm);
    PK2 p2 = epi_quad(d2, cb + 64 + 32 + q * 4, cb + 128 + 32 + q * 4, rs, nm);
    PK2 p3 = epi_quad(d3, cb + 64 + 48 + q * 4, cb + 128 + 48 + q * 4, rs, nm);
    BF o;
    o.lo[0] = p0.a[0]; o.lo[1] = p0.a[1]; o.lo[2] = p0.b[0]; o.lo[3] = p0.b[1];
    o.lo[4] = p1.a[0]; o.lo[5] = p1.a[1]; o.lo[6] = p1.b[0]; o.lo[7] = p1.b[1];
    o.hi[0] = p2.a[0]; o.hi[1] = p2.a[1]; o.hi[2] = p2.b[0]; o.hi[3] = p2.b[1];
    o.hi[4] = p3.a[0]; o.hi[5] = p3.a[1]; o.hi[6] = p3.b[0]; o.hi[7] = p3.b[1];
    return o;
}

__device__ __forceinline__ BF l0_sample(const _Float16* xs, int slot, int q,
                                        v8h A0, v8h A1, v8h A2, v8h A3,
                                        v4f b0, v4f b1, v4f b2, v4f b3,
                                        const float* cf) {
    v8h bfr = {};
    if (q == 0) bfr = *(const v8h*)(xs + (size_t)slot * 8);
    v4f d0 = MFMA16(A0, bfr, b0);
    v4f d1 = MFMA16(A1, bfr, b1);
    v4f d2 = MFMA16(A2, bfr, b2);
    v4f d3 = MFMA16(A3, bfr, b3);
    return layer_epilogue(d0, d1, d2, d3, cf, q);
}

__device__ __forceinline__ BF mid_sample(BF h,
                                         v8h a00, v8h a01, v8h a10, v8h a11,
                                         v8h a20, v8h a21, v8h a30, v8h a31,
                                         v4f b0, v4f b1, v4f b2, v4f b3,
                                         const float* cb, int q) {
    v4f d0 = MFMA16(a00, h.lo, b0); d0 = MFMA16(a01, h.hi, d0);
    v4f d1 = MFMA16(a10, h.lo, b1); d1 = MFMA16(a11, h.hi, d1);
    v4f d2 = MFMA16(a20, h.lo, b2); d2 = MFMA16(a21, h.hi, d2);
    v4f d3 = MFMA16(a30, h.lo, b3); d3 = MFMA16(a31, h.hi, d3);
    return layer_epilogue(d0, d1, d2, d3, cb, q);
}

__device__ __forceinline__ int in_valid(int rel, int a0, int a1, int a2, int a3) {
    return (rel < a0) | ((rel >= RHALF - a1) & (rel < RHALF + a2)) |
           (rel >= CAP - a3);
}

__global__ __launch_bounds__(256, 3) void mlp_kernel(
    const int* __restrict__ iws, const _Float16* __restrict__ xs,
    const unsigned char* __restrict__ imgbase, float* __restrict__ out) {
    const int m = blockIdx.y;
    const int a0 = iws[O_CURSORS + (m * 4 + 0) * CSTRIDE];
    const int a1 = iws[O_CURSORS + (m * 4 + 1) * CSTRIDE];
    const int a2 = iws[O_CURSORS + (m * 4 + 2) * CSTRIDE];
    const int a3 = iws[O_CURSORS + (m * 4 + 3) * CSTRIDE];
    // valid rel: [0,a0) U [RHALF-a1, RHALF+a2) U [CAP-a3, CAP)
    const int C0 = blockIdx.x * 256, C1 = C0 + 256;
    if (!((C0 < a0) | ((C1 > RHALF - a1) & (C0 < RHALF + a2)) | (C1 > CAP - a3)))
        return;

    const int t = threadIdx.x, w = t >> 6, lane = t & 63;
    const int c = lane & 15, q = lane >> 4;
    const int wb = C0 + w * 64;
    if (!((wb < a0) | ((wb + 64 > RHALF - a1) & (wb < RHALF + a2)) |
          (wb + 64 > CAP - a3)))
        return;

    const _Float16* img = (const _Float16*)(imgbase + (size_t)m * IMG_BYTES);
    const float* cf = (const float*)(imgbase + (size_t)m * IMG_BYTES + CONST_B);
    const int* order = iws + O_ORDER;

    const int r0 = wb + 0 + c,  r1 = wb + 16 + c;
    const int r2 = wb + 32 + c, r3 = wb + 48 + c;
    const int v0 = in_valid(r0, a0, a1, a2, a3);
    const int v1 = in_valid(r1, a0, a1, a2, a3);
    const int v2 = in_valid(r2, a0, a1, a2, a3);
    const int v3 = in_valid(r3, a0, a1, a2, a3);
    const int s0 = m * CAP + r0, s1 = m * CAP + r1;
    const int s2 = m * CAP + r2, s3 = m * CAP + r3;
    const int sid0 = order[s0], sid1 = order[s1];
    const int sid2 = order[s2], sid3 = order[s3];

    BF h0, h1, h2, h3;

    // ---- layer 0: K=6 padded to 32; B from packed xs ----
    {
        v8h A0 = *(const v8h*)(img + 0 * 512 + lane * 8);
        v8h A1 = *(const v8h*)(img + 1 * 512 + lane * 8);
        v8h A2 = *(const v8h*)(img + 2 * 512 + lane * 8);
        v8h A3 = *(const v8h*)(img + 3 * 512 + lane * 8);
        v4f b0 = *(const v4f*)(cf + 0  + q * 4);
        v4f b1 = *(const v4f*)(cf + 16 + q * 4);
        v4f b2 = *(const v4f*)(cf + 32 + q * 4);
        v4f b3 = *(const v4f*)(cf + 48 + q * 4);
        h0 = l0_sample(xs, s0, q, A0, A1, A2, A3, b0, b1, b2, b3, cf);
        h1 = l0_sample(xs, s1, q, A0, A1, A2, A3, b0, b1, b2, b3, cf);
        h2 = l0_sample(xs, s2, q, A0, A1, A2, A3, b0, b1, b2, b3, cf);
        h3 = l0_sample(xs, s3, q, A0, A1, A2, A3, b0, b1, b2, b3, cf);
    }

    // ---- layers 1..3: register-resident chaining ----
#pragma unroll
    for (int l = 1; l <= 3; l++) {
        const _Float16* wp = img + 2048 + (l - 1) * 4096 + lane * 8;
        v8h a00 = *(const v8h*)(wp + 0 * 512);
        v8h a01 = *(const v8h*)(wp + 1 * 512);
        v8h a10 = *(const v8h*)(wp + 2 * 512);
        v8h a11 = *(const v8h*)(wp + 3 * 512);
        v8h a20 = *(const v8h*)(wp + 4 * 512);
        v8h a21 = *(const v8h*)(wp + 5 * 512);
        v8h a30 = *(const v8h*)(wp + 6 * 512);
        v8h a31 = *(const v8h*)(wp + 7 * 512);
        const float* cb = cf + l * 192;
        v4f b0 = *(const v4f*)(cb + 0  + q * 4);
        v4f b1 = *(const v4f*)(cb + 16 + q * 4);
        v4f b2 = *(const v4f*)(cb + 32 + q * 4);
        v4f b3 = *(const v4f*)(cb + 48 + q * 4);
        h0 = mid_sample(h0, a00, a01, a10, a11, a20, a21, a30, a31, b0, b1, b2, b3, cb, q);
        h1 = mid_sample(h1, a00, a01, a10, a11, a20, a21, a30, a31, b0, b1, b2, b3, cb, q);
        h2 = mid_sample(h2, a00, a01, a10, a11, a20, a21, a30, a31, b0, b1, b2, b3, cb, q);
        h3 = mid_sample(h3, a00, a01, a10, a11, a20, a21, a30, a31, b0, b1, b2, b3, cb, q);
    }

    // ---- layer 4: 64 -> 3 (rows physical, padded to 16) ----
    {
        const _Float16* wp = img + 14336 + lane * 8;
        v8h A0 = *(const v8h*)(wp);
        v8h A1 = *(const v8h*)(wp + 512);
        v4f b4i = {cf[768], cf[769], cf[770], 0.0f};
        v4f D0 = MFMA16(A0, h0.lo, b4i); D0 = MFMA16(A1, h0.hi, D0);
        v4f D1 = MFMA16(A0, h1.lo, b4i); D1 = MFMA16(A1, h1.hi, D1);
        v4f D2 = MFMA16(A0, h2.lo, b4i); D2 = MFMA16(A1, h2.hi, D2);
        v4f D3 = MFMA16(A0, h3.lo, b4i); D3 = MFMA16(A1, h3.hi, D3);
        if (q == 0) {
            if (v0) { float* op = out + (size_t)sid0 * 3; op[0] = D0[0]; op[1] = D0[1]; op[2] = D0[2]; }
            if (v1) { float* op = out + (size_t)sid1 * 3; op[0] = D1[0]; op[1] = D1[1]; op[2] = D1[2]; }
            if (v2) { float* op = out + (size_t)sid2 * 3; op[0] = D2[0]; op[1] = D2[1]; op[2] = D2[2]; }
            if (v3) { float* op = out + (size_t)sid3 * 3; op[0] = D3[0]; op[1] = D3[1]; op[2] = D3[2]; }
        }
    }
}

// -------------------------------------------------------------- launch ----
extern "C" void kernel_launch(void* const* d_in, const int* in_sizes, int n_in,
                              void* d_out, int out_size, void* d_ws, size_t ws_size,
                              hipStream_t stream) {
    const float* x  = (const float*)d_in[0];
    const int*  idx = (const int*)d_in[1];
    const float* W0 = (const float*)d_in[2];
    const float* B0 = (const float*)d_in[3];
    const float* G0 = (const float*)d_in[4];
    const float* H0 = (const float*)d_in[5];
    const float* W1 = (const float*)d_in[6];
    const float* B1 = (const float*)d_in[7];
    const float* G1 = (const float*)d_in[8];
    const float* H1 = (const float*)d_in[9];
    const float* W2 = (const float*)d_in[10];
    const float* B2 = (const float*)d_in[11];
    const float* G2 = (const float*)d_in[12];
    const float* H2 = (const float*)d_in[13];
    const float* W3 = (const float*)d_in[14];
    const float* B3 = (const float*)d_in[15];
    const float* G3 = (const float*)d_in[16];
    const float* H3 = (const float*)d_in[17];
    const float* W4 = (const float*)d_in[18];
    const float* B4 = (const float*)d_in[19];
    float* out = (float*)d_out;

    int n = in_sizes[1];
    int* iws = (int*)d_ws;
    _Float16* xs = (_Float16*)((char*)d_ws + (size_t)IWS_INTS * 4);
    unsigned char* imgbase =
        (unsigned char*)d_ws + (size_t)IWS_INTS * 4 + (size_t)NM * CAP * 16;

    (void)hipMemsetAsync(d_ws, 0, NM * 4 * CSTRIDE * sizeof(int), stream);
    bucket_img_kernel<<<dim3(NBLKB), 256, 0, stream>>>(
        idx, x, n, W0, W1, W2, W3, W4,
        B0, G0, H0, B1, G1, H1, B2, G2, H2, B3, G3, H3, B4, iws, xs, imgbase);
    // grid.x = CAP/256 = 19 chunks of 256 samples per model.
    mlp_kernel<<<dim3(19, NM), 256, 0, stream>>>(iws, xs, imgbase, out);
}